// Round 8
// baseline (83.287 us; speedup 1.0000x reference)
//
#include <hip/hip_runtime.h>

// ConvCapsuleLayer r8: SPLIT conv (fp16 MFMA GEMM -> votes in ws) + routing kernel.
// Fallback to r6 fused kernel if ws_size too small for the 67MB votes buffer.

typedef __attribute__((ext_vector_type(8))) _Float16 f16x8;
typedef __attribute__((ext_vector_type(16))) float f32x16;

__device__ __forceinline__ unsigned short f2h(float x) {
  union { _Float16 h; unsigned short u; } v;
  v.h = (_Float16)x;
  return v.u;
}

// Bank swizzle for votes LDS: XOR byte bits 4-6 with (ch>>3)&7.
#define VSWZ(byteoff, ch) ((byteoff) ^ ((((ch) >> 3) & 7) << 4))

// W[5][5][16][256] f32 -> wsh fp16 [khkw 25][ch 256][ia 16]
__global__ __launch_bounds__(256) void wprep_kernel(
    const float* __restrict__ W, unsigned short* __restrict__ wsh) {
  int t = blockIdx.x * 256 + threadIdx.x;      // 102400 total
  int khkw = t >> 12;
  int rem  = t & 4095;
  int ch = rem >> 4, ia = rem & 15;
  wsh[t] = f2h(W[khkw * 4096 + ia * 256 + ch]);
}

// inp f32 [b 16][h 32][w 32][i 8][ia 16] -> xt fp16 [n 128][h][w][ia 16], n: (i=n>>4, b=n&15)
__global__ __launch_bounds__(256) void xprep_kernel(
    const float* __restrict__ inp, _Float16* __restrict__ xt) {
  int t = blockIdx.x * 256 + threadIdx.x;      // 524288 quads
  int n = t >> 12;
  int r = t & 4095;                            // (h*32+w)*4 + iaq
  int hw = r >> 2, iaq = r & 3;
  int b = n & 15, i = n >> 4;
  float4 v = *(const float4*)(inp + (((size_t)b * 1024 + hw) * 8 + i) * 16 + iaq * 4);
  union { _Float16 hx[4]; unsigned long long u; } pk;
  pk.hx[0] = (_Float16)v.x; pk.hx[1] = (_Float16)v.y;
  pk.hx[2] = (_Float16)v.z; pk.hx[3] = (_Float16)v.w;
  *(unsigned long long*)(xt + ((size_t)n * 1024 + hw) * 16 + iaq * 4) = pk.u;
}

// ---------------- Kernel A: conv -> votes fp16 [pos 16384][ch 256][ii 8] ----------------
// Block: M=64 rows (8 w x 8 ii), N=256 ch, 4 waves. X staged from xt (fp16, b128 copies).
__global__ __launch_bounds__(256, 4) void conv_votes_kernel(
    const _Float16* __restrict__ xt,          // [128][32][32][16] fp16
    const unsigned short* __restrict__ wsh,   // [25][256][16] fp16
    _Float16* __restrict__ votesG)            // [16384][256][8] fp16
{
  __shared__ char smem[32768];
  // conv: X fp16 [kh 5][ii 8, stride 400B][wl 12][ia 16] = 16000 B @0
  // then votes fp16 [w 8][ch 256][ii 8] swizzled = 32768 @0 (aliases X)
  const _Float16* wshh = (const _Float16*)wsh;
  char* votesB = smem;

  const int tid  = threadIdx.x;
  const int wid  = tid >> 6;
  const int lane = tid & 63;
  const int sub  = lane >> 5;
  const int ln31 = lane & 31;

  const int bid = blockIdx.x;         // 2048 = ((bb*32 + h)*4 + wq)
  const int wq = bid & 3;
  const int h  = (bid >> 2) & 31;
  const int bb = bid >> 7;

  // ---- stage 5 X rows from xt: 960 x 16B units ----
  for (int e = tid; e < 960; e += 256) {
    int kh = e / 192; int r1 = e - kh * 192;
    int ii = r1 / 24; int r2 = r1 - ii * 24;
    int wl = r2 >> 1; int half = r2 & 1;
    int hh = h + kh - 2;
    int wsrc = wq * 8 + wl - 2;
    int n = bb * 8 + ii;
    union { f16x8 v; unsigned long long u[2]; } d;
    d.u[0] = 0ull; d.u[1] = 0ull;
    if ((unsigned)hh < 32u && (unsigned)wsrc < 32u)
      d.v = *(const f16x8*)(xt + (((size_t)n * 32 + hh) * 32 + wsrc) * 16 + half * 8);
    *(f16x8*)(smem + kh * 3200 + ii * 400 + wl * 32 + half * 16) = d.v;
  }
  __syncthreads();

  // ---- conv: 25 taps ----
  f32x16 acc[2][2];
  #pragma unroll
  for (int mt = 0; mt < 2; ++mt)
    #pragma unroll
    for (int nt = 0; nt < 2; ++nt)
      #pragma unroll
      for (int e = 0; e < 16; ++e) acc[mt][nt][e] = 0.f;

  #pragma unroll 1
  for (int kh = 0; kh < 5; ++kh) {
    #pragma unroll
    for (int kw = 0; kw < 5; ++kw) {
      f16x8 afrag[2], bfrag[2];
      #pragma unroll
      for (int mt = 0; mt < 2; ++mt) {
        int r = mt * 32 + ln31;                 // row: w_local = r>>3, ii = r&7
        afrag[mt] = *(const f16x8*)(smem + kh * 3200 + (r & 7) * 400 +
                                    ((r >> 3) + kw) * 32 + sub * 16);
      }
      #pragma unroll
      for (int nt = 0; nt < 2; ++nt) {
        int ch = wid * 64 + nt * 32 + ln31;
        bfrag[nt] = *(const f16x8*)(wshh + (size_t)(kh * 5 + kw) * 4096 + ch * 16 + sub * 8);
      }
      #pragma unroll
      for (int mt = 0; mt < 2; ++mt)
        #pragma unroll
        for (int nt = 0; nt < 2; ++nt)
          acc[mt][nt] = __builtin_amdgcn_mfma_f32_32x32x16_f16(
              afrag[mt], bfrag[nt], acc[mt][nt], 0, 0, 0);
    }
  }

  // ---- acc -> LDS fp16 [w][ch][ii] swizzled, then coalesced global store ----
  __syncthreads();   // X dead; votes alias
  #pragma unroll
  for (int mt = 0; mt < 2; ++mt)
    #pragma unroll
    for (int nt = 0; nt < 2; ++nt) {
      int ch = wid * 64 + nt * 32 + ln31;
      #pragma unroll
      for (int q = 0; q < 4; ++q) {
        int w = mt * 4 + q;
        union { _Float16 hx[4]; unsigned long long u; } pk;
        #pragma unroll
        for (int t = 0; t < 4; ++t) pk.hx[t] = (_Float16)acc[mt][nt][q * 4 + t];
        int byte = (w * 256 + ch) * 16 + sub * 8;
        *(unsigned long long*)(votesB + VSWZ(byte, ch)) = pk.u;
      }
    }
  __syncthreads();

  const size_t pos0 = (size_t)(bb * 32 + h) * 32 + wq * 8;
  #pragma unroll
  for (int w = 0; w < 8; ++w) {
    f16x8 vv = *(const f16x8*)(votesB + VSWZ((w * 256 + tid) * 16, tid));
    *(f16x8*)(votesG + ((pos0 + w) * 256 + tid) * 8) = vv;
  }
}

// ---------------- Kernel B: routing from votes ----------------
__global__ __launch_bounds__(256, 4) void routing_kernel(
    const _Float16* __restrict__ votesG,      // [16384][256][8] fp16
    const float* __restrict__ bias,           // [256] f32
    float* __restrict__ out)                  // [16384][256] f32
{
  __shared__ char smem[39936];
  char* votesB = smem;                         // fp16 [w 8][ch 256][ii 8] swizzled
  _Float16* actH   = (_Float16*)(smem + 32768);
  float*    logitL = (float*)(smem + 36864);
  _Float16* routeH = (_Float16*)(smem + 38912);

  const int tid = threadIdx.x;
  const int bid = blockIdx.x;                  // 2048 = ((bb*32+h)*4 + wq)
  const size_t pos0 = (size_t)(bid >> 2) * 32 + (bid & 3) * 8;

  // preload votes tile 32KB, swizzled
  for (int u = tid; u < 2048; u += 256) {
    int w = u >> 8, ch = u & 255;
    f16x8 vv = *(const f16x8*)(votesG + ((pos0 + w) * 256 + ch) * 8);
    *(f16x8*)(votesB + VSWZ((w * 256 + ch) * 16, ch)) = vv;
  }
  __syncthreads();

  const int c_own = tid >> 5;
  const float bv = bias[tid];
  const int ag_w = tid >> 5;          // agreement task: (w, c, g)
  const int ag_c = (tid >> 2) & 7;
  const int ag_g = tid & 3;

  f16x8 vreg[8];
  #pragma unroll
  for (int w = 0; w < 8; ++w)
    vreg[w] = *(const f16x8*)(votesB + VSWZ((w * 256 + tid) * 16, tid));

  #pragma unroll 1
  for (int rt = 0; rt < 3; ++rt) {
    if (rt > 0) {
      if (tid < 64) {                 // softmax over c per (w, ii)
        int wv = tid >> 3, ii = tid & 7;
        float l[8];
        #pragma unroll
        for (int c = 0; c < 8; ++c) l[c] = logitL[(wv * 8 + ii) * 8 + c];
        float mx = fmaxf(fmaxf(fmaxf(l[0], l[1]), fmaxf(l[2], l[3])),
                         fmaxf(fmaxf(l[4], l[5]), fmaxf(l[6], l[7])));
        float den = 0.f;
        #pragma unroll
        for (int c = 0; c < 8; ++c) den += __expf(l[c] - mx);
        float inv = 1.f / den;
        #pragma unroll
        for (int c = 0; c < 8; ++c)
          routeH[(wv * 8 + c) * 8 + ii] = (_Float16)(__expf(l[c] - mx) * inv);
      }
      __syncthreads();
    }
    #pragma unroll
    for (int w = 0; w < 8; ++w) {
      float pre = bv;
      if (rt == 0) {
        float s = 0.f;
        #pragma unroll
        for (int i = 0; i < 8; ++i) s += (float)vreg[w][i];
        pre = fmaf(0.125f, s, pre);
      } else {
        f16x8 rp = *(const f16x8*)(routeH + (w * 8 + c_own) * 8);
        #pragma unroll
        for (int i = 0; i < 8; ++i) pre = fmaf((float)rp[i], (float)vreg[w][i], pre);
      }
      float nsq = pre * pre;
      #pragma unroll
      for (int m = 16; m >= 1; m >>= 1) nsq += __shfl_xor(nsq, m, 64);
      float av = pre * (sqrtf(nsq) / (1.f + nsq));
      if (rt == 2)
        out[(pos0 + w) * 256 + tid] = av;
      else
        actH[w * 256 + tid] = (_Float16)av;
    }
    if (rt < 2) {
      __syncthreads();
      float dot8[8];
      #pragma unroll
      for (int i = 0; i < 8; ++i) dot8[i] = 0.f;
      #pragma unroll
      for (int j0 = 0; j0 < 8; ++j0) {
        int a = ag_g * 8 + ((j0 + ag_c) & 7);
        int ch = ag_c * 32 + a;
        int byte = (ag_w * 256 + ch) * 16;
        f16x8 vp = *(const f16x8*)(votesB + VSWZ(byte, ch));
        float av = (float)actH[ag_w * 256 + ch];
        #pragma unroll
        for (int ii = 0; ii < 8; ++ii) dot8[ii] = fmaf((float)vp[ii], av, dot8[ii]);
      }
      #pragma unroll
      for (int ii = 0; ii < 8; ++ii) {
        dot8[ii] += __shfl_xor(dot8[ii], 1, 64);
        dot8[ii] += __shfl_xor(dot8[ii], 2, 64);
      }
      if (ag_g == 0) {
        #pragma unroll
        for (int ii = 0; ii < 8; ++ii) {
          int idx = (ag_w * 8 + ii) * 8 + ag_c;
          if (rt == 0) logitL[idx] = dot8[ii];
          else         logitL[idx] += dot8[ii];
        }
      }
      __syncthreads();
    }
  }
}

// ---------------- Fallback: r6 fused kernel (verbatim) ----------------
__global__ __launch_bounds__(256, 4) void fused_kernel(
    const float* __restrict__ inp, const unsigned short* __restrict__ wsh,
    const float* __restrict__ bias, float* __restrict__ out)
{
  __shared__ char smem[39936];
  const _Float16* wshh = (const _Float16*)wsh;
  char* votesB = smem;
  _Float16* actH   = (_Float16*)(smem + 32768);
  float*    logitL = (float*)(smem + 36864);
  _Float16* routeH = (_Float16*)(smem + 38912);

  const int tid  = threadIdx.x;
  const int wid  = tid >> 6;
  const int lane = tid & 63;
  const int sub  = lane >> 5;
  const int ln31 = lane & 31;

  const int bid = blockIdx.x;
  const int wq = bid & 3;
  const int h  = (bid >> 2) & 31;
  const int bb = bid >> 7;
  const int i_src  = bb >> 1;
  const int b_base = (bb & 1) * 8;

  for (int e = tid; e < 1920; e += 256) {
    int kh = e / 384; int r1 = e - kh * 384;
    int ii = r1 / 48; int r2 = r1 - ii * 48;
    int wl = r2 >> 2; int iaq = r2 & 3;
    int hh = h + kh - 2;
    int wsrc = wq * 8 + wl - 2;
    float4 v = make_float4(0.f, 0.f, 0.f, 0.f);
    if ((unsigned)hh < 32u && (unsigned)wsrc < 32u)
      v = *(const float4*)(inp +
          ((((size_t)(b_base + ii) * 32 + hh) * 32 + wsrc) * 8 + i_src) * 16 + iaq * 4);
    union { _Float16 hx[4]; unsigned long long u; } pk;
    pk.hx[0] = (_Float16)v.x; pk.hx[1] = (_Float16)v.y;
    pk.hx[2] = (_Float16)v.z; pk.hx[3] = (_Float16)v.w;
    *(unsigned long long*)(smem + kh * 3200 + ii * 400 + wl * 32 + iaq * 8) = pk.u;
  }
  __syncthreads();

  f32x16 acc[2][2];
  #pragma unroll
  for (int mt = 0; mt < 2; ++mt)
    #pragma unroll
    for (int nt = 0; nt < 2; ++nt)
      #pragma unroll
      for (int e = 0; e < 16; ++e) acc[mt][nt][e] = 0.f;

  #pragma unroll 1
  for (int kh = 0; kh < 5; ++kh) {
    #pragma unroll
    for (int kw = 0; kw < 5; ++kw) {
      f16x8 afrag[2], bfrag[2];
      #pragma unroll
      for (int mt = 0; mt < 2; ++mt) {
        int r = mt * 32 + ln31;
        afrag[mt] = *(const f16x8*)(smem + kh * 3200 + (r & 7) * 400 +
                                    ((r >> 3) + kw) * 32 + sub * 16);
      }
      #pragma unroll
      for (int nt = 0; nt < 2; ++nt) {
        int ch = wid * 64 + nt * 32 + ln31;
        bfrag[nt] = *(const f16x8*)(wshh + (size_t)(kh * 5 + kw) * 4096 + ch * 16 + sub * 8);
      }
      #pragma unroll
      for (int mt = 0; mt < 2; ++mt)
        #pragma unroll
        for (int nt = 0; nt < 2; ++nt)
          acc[mt][nt] = __builtin_amdgcn_mfma_f32_32x32x16_f16(
              afrag[mt], bfrag[nt], acc[mt][nt], 0, 0, 0);
    }
  }

  __syncthreads();
  #pragma unroll
  for (int mt = 0; mt < 2; ++mt)
    #pragma unroll
    for (int nt = 0; nt < 2; ++nt) {
      int ch = wid * 64 + nt * 32 + ln31;
      #pragma unroll
      for (int q = 0; q < 4; ++q) {
        int w = mt * 4 + q;
        union { _Float16 hx[4]; unsigned long long u; } pk;
        #pragma unroll
        for (int t = 0; t < 4; ++t) pk.hx[t] = (_Float16)acc[mt][nt][q * 4 + t];
        int byte = (w * 256 + ch) * 16 + sub * 8;
        *(unsigned long long*)(votesB + VSWZ(byte, ch)) = pk.u;
      }
    }
  __syncthreads();

  const int c_own = tid >> 5;
  const float bv = bias[tid];
  const int ag_w = tid >> 5;
  const int ag_c = (tid >> 2) & 7;
  const int ag_g = tid & 3;

  f16x8 vreg[8];
  #pragma unroll
  for (int w = 0; w < 8; ++w)
    vreg[w] = *(const f16x8*)(votesB + VSWZ((w * 256 + tid) * 16, tid));

  #pragma unroll 1
  for (int rt = 0; rt < 3; ++rt) {
    if (rt > 0) {
      if (tid < 64) {
        int wv = tid >> 3, ii = tid & 7;
        float l[8];
        #pragma unroll
        for (int c = 0; c < 8; ++c) l[c] = logitL[(wv * 8 + ii) * 8 + c];
        float mx = fmaxf(fmaxf(fmaxf(l[0], l[1]), fmaxf(l[2], l[3])),
                         fmaxf(fmaxf(l[4], l[5]), fmaxf(l[6], l[7])));
        float den = 0.f;
        #pragma unroll
        for (int c = 0; c < 8; ++c) den += __expf(l[c] - mx);
        float inv = 1.f / den;
        #pragma unroll
        for (int c = 0; c < 8; ++c)
          routeH[(wv * 8 + c) * 8 + ii] = (_Float16)(__expf(l[c] - mx) * inv);
      }
      __syncthreads();
    }
    #pragma unroll
    for (int w = 0; w < 8; ++w) {
      float pre = bv;
      if (rt == 0) {
        float s = 0.f;
        #pragma unroll
        for (int i = 0; i < 8; ++i) s += (float)vreg[w][i];
        pre = fmaf(0.125f, s, pre);
      } else {
        f16x8 rp = *(const f16x8*)(routeH + (w * 8 + c_own) * 8);
        #pragma unroll
        for (int i = 0; i < 8; ++i) pre = fmaf((float)rp[i], (float)vreg[w][i], pre);
      }
      float nsq = pre * pre;
      #pragma unroll
      for (int m = 16; m >= 1; m >>= 1) nsq += __shfl_xor(nsq, m, 64);
      float av = pre * (sqrtf(nsq) / (1.f + nsq));
      if (rt == 2)
        out[((size_t)((bb * 32 + h) * 32 + wq * 8 + w)) * 256 + tid] = av;
      else
        actH[w * 256 + tid] = (_Float16)av;
    }
    if (rt < 2) {
      __syncthreads();
      float dot8[8];
      #pragma unroll
      for (int i = 0; i < 8; ++i) dot8[i] = 0.f;
      #pragma unroll
      for (int j0 = 0; j0 < 8; ++j0) {
        int a = ag_g * 8 + ((j0 + ag_c) & 7);
        int ch = ag_c * 32 + a;
        int byte = (ag_w * 256 + ch) * 16;
        f16x8 vp = *(const f16x8*)(votesB + VSWZ(byte, ch));
        float av = (float)actH[ag_w * 256 + ch];
        #pragma unroll
        for (int ii = 0; ii < 8; ++ii) dot8[ii] = fmaf((float)vp[ii], av, dot8[ii]);
      }
      #pragma unroll
      for (int ii = 0; ii < 8; ++ii) {
        dot8[ii] += __shfl_xor(dot8[ii], 1, 64);
        dot8[ii] += __shfl_xor(dot8[ii], 2, 64);
      }
      if (ag_g == 0) {
        #pragma unroll
        for (int ii = 0; ii < 8; ++ii) {
          int idx = (ag_w * 8 + ii) * 8 + ag_c;
          if (rt == 0) logitL[idx] = dot8[ii];
          else         logitL[idx] += dot8[ii];
        }
      }
      __syncthreads();
    }
  }
}

extern "C" void kernel_launch(void* const* d_in, const int* in_sizes, int n_in,
                              void* d_out, int out_size, void* d_ws, size_t ws_size,
                              hipStream_t stream) {
  (void)in_sizes; (void)n_in; (void)out_size;
  const float* inp  = (const float*)d_in[0];
  const float* W    = (const float*)d_in[1];
  const float* bv   = (const float*)d_in[2];
  float* out        = (float*)d_out;

  unsigned short* wsh = (unsigned short*)d_ws;                    // 204800 B
  _Float16* xt    = (_Float16*)((char*)d_ws + 204800);            // 4194304 B
  _Float16* votes = (_Float16*)((char*)d_ws + 4399104);           // 67108864 B
  const size_t need = 4399104ull + 67108864ull;

  hipLaunchKernelGGL(wprep_kernel, dim3(400), dim3(256), 0, stream, W, wsh);
  if (ws_size >= need) {
    hipLaunchKernelGGL(xprep_kernel, dim3(2048), dim3(256), 0, stream, inp, xt);
    hipLaunchKernelGGL(conv_votes_kernel, dim3(2048), dim3(256), 0, stream, xt, wsh, votes);
    hipLaunchKernelGGL(routing_kernel, dim3(2048), dim3(256), 0, stream, votes, bv, out);
  } else {
    hipLaunchKernelGGL(fused_kernel, dim3(2048), dim3(256), 0, stream, inp, wsh, bv, out);
  }
}

// Round 9
// 65.363 us; speedup vs baseline: 1.2742x; 1.2742x over previous
//
#include <hip/hip_runtime.h>

// ConvCapsuleLayer r9: fused fp16-MFMA conv + routing rebuilt on v_dot2_f32_f16.
// Block = 256 thr (4 waves), M=32 rows (4 w-pos x 8 ii), N=256 ch.
// votesT LDS [w][ii][chunk][a] (atom-contiguous) -> agreement = 256 direct tasks,
// 16 fdot2 each, no shuffles. Weighted sum via fdot2 on fp16 route pairs.

typedef __attribute__((ext_vector_type(2))) _Float16 f16x2;
typedef __attribute__((ext_vector_type(8))) _Float16 f16x8;
typedef __attribute__((ext_vector_type(16))) float f32x16;

union f16x8u { f16x8 v; f16x2 d[4]; unsigned short s[8]; unsigned long long u[2]; };

__device__ __forceinline__ unsigned short f2h(float x) {
  union { _Float16 h; unsigned short u; } v;
  v.h = (_Float16)x;
  return v.u;
}

// W[5][5][16][256] f32 -> wsh fp16 [khkw 25][ch 256][ia 16]
__global__ __launch_bounds__(256) void wprep_kernel(
    const float* __restrict__ W, unsigned short* __restrict__ wsh) {
  int t = blockIdx.x * 256 + threadIdx.x;      // 102400 total
  int khkw = t >> 12;
  int rem  = t & 4095;
  int ch = rem >> 4, ia = rem & 15;
  wsh[t] = f2h(W[khkw * 4096 + ia * 256 + ch]);
}

// LDS map (19968 B):
//   conv phase:  X fp16 [kh 5][ii 8, stride 272B][wl 8][ia 16] = 10880 B @0
//   routing:     votesT fp16 [w 4][ii 8][chunk 32][a 8] = 16384 @0 (aliases X)
//                  chunk(q,c,ii) = q*8 + (((c+q)&7) ^ ii)   (bank spread, bijective)
//                actT  fp16 [w 4][q 4][c 8][a 8] = 2048 @16384
//                logitL f32 [w 4][ii 8][c 8]     = 1024 @18432
//                routeH fp16 [w 4][c 8][ii 8]    =  512 @19456
__global__ __launch_bounds__(256, 4) void capsconv_mfma_kernel(
    const float* __restrict__ inp,            // [16][32][32][8][16] f32
    const unsigned short* __restrict__ wsh,   // [25][256][16] fp16
    const float* __restrict__ bias,           // [256] f32
    float* __restrict__ out)                  // [16][32][32][256] f32
{
  __shared__ char smem[19968];
  const _Float16* wshh = (const _Float16*)wsh;
  float* logitL = (float*)(smem + 18432);

  const int tid  = threadIdx.x;
  const int wid  = tid >> 6;          // wave 0..3 -> ch quarter
  const int lane = tid & 63;
  const int sub  = lane >> 5;
  const int ln31 = lane & 31;

  const int bid = blockIdx.x;         // 4096 = ((bb*32 + h)*8 + wq)
  const int wq = bid & 7;
  const int h  = (bid >> 3) & 31;
  const int bb = bid >> 8;
  const int i_src  = bb >> 1;         // TF reshape scramble (verified r1/r4)
  const int b_base = (bb & 1) * 8;

  // ---------------- stage 5 X rows, PO2 decode (1280 quads) ----------------
  #pragma unroll
  for (int s = 0; s < 5; ++s) {
    int e = tid + s * 256;
    int kh  = e >> 8;
    int ii  = (e >> 5) & 7;
    int wl  = (e >> 2) & 7;
    int iaq = e & 3;
    int hh = h + kh - 2;
    int wsrc = wq * 4 + wl - 2;
    float4 v = make_float4(0.f, 0.f, 0.f, 0.f);
    if ((unsigned)hh < 32u && (unsigned)wsrc < 32u)
      v = *(const float4*)(inp +
          ((((size_t)(b_base + ii) * 32 + hh) * 32 + wsrc) * 8 + i_src) * 16 + iaq * 4);
    union { _Float16 hx[4]; unsigned long long u; } pk;
    pk.hx[0] = (_Float16)v.x; pk.hx[1] = (_Float16)v.y;
    pk.hx[2] = (_Float16)v.z; pk.hx[3] = (_Float16)v.w;
    *(unsigned long long*)(smem + kh * 2176 + ii * 272 + wl * 32 + iaq * 8) = pk.u;
  }
  __syncthreads();

  // ---------------- conv: 25 taps, barrier-free ----------------
  f32x16 acc[2];
  #pragma unroll
  for (int nt = 0; nt < 2; ++nt)
    #pragma unroll
    for (int e = 0; e < 16; ++e) acc[nt][e] = 0.f;

  #pragma unroll 1
  for (int kh = 0; kh < 5; ++kh) {
    #pragma unroll
    for (int kw = 0; kw < 5; ++kw) {
      // rows r = ln31: w_local = r>>3, ii = r&7
      f16x8 afrag = *(const f16x8*)(smem + kh * 2176 + (ln31 & 7) * 272 +
                                    ((ln31 >> 3) + kw) * 32 + sub * 16);
      #pragma unroll
      for (int nt = 0; nt < 2; ++nt) {
        int ch = wid * 64 + nt * 32 + ln31;
        f16x8 bfrag = *(const f16x8*)(wshh + (size_t)(kh * 5 + kw) * 4096 + ch * 16 + sub * 8);
        acc[nt] = __builtin_amdgcn_mfma_f32_32x32x16_f16(afrag, bfrag, acc[nt], 0, 0, 0);
      }
    }
  }

  // ---------------- votes -> votesT [w][ii][chunk][a] ----------------
  __syncthreads();   // X region dead; votesT aliases it
  ((unsigned short*)(smem + 19456))[tid] = 0x3000;   // routeH = 0.125 (exact fp16)
  #pragma unroll
  for (int nt = 0; nt < 2; ++nt) {
    int ch = wid * 64 + nt * 32 + ln31;
    int c = (ch >> 5) & 7, q = (ch >> 3) & 3, a = ch & 7;
    #pragma unroll
    for (int w = 0; w < 4; ++w)
      #pragma unroll
      for (int t = 0; t < 4; ++t) {
        int ii = t + 4 * sub;          // C/D row = t + 8w + 4sub (verified r4-r7)
        int bp = q * 8 + (((c + q) & 7) ^ ii);
        *(unsigned short*)(smem + w * 4096 + ii * 512 + bp * 16 + a * 2) =
            f2h(acc[nt][w * 4 + t]);
      }
  }
  __syncthreads();

  // ---------------- routing ----------------
  const int c_t = (tid >> 5) & 7;     // owned channel decode (ch = tid)
  const int q_t = (tid >> 3) & 3;
  const int a_t = tid & 7;
  const float bv = bias[tid];
  const int aw  = tid >> 6;           // agreement task (w, ii, c)
  const int aii = (tid >> 3) & 7;
  const int ac  = tid & 7;

  // vreg[w][ii] = votes for owned ch (one-time gather from votesT)
  f16x8 vreg[4];
  #pragma unroll
  for (int w = 0; w < 4; ++w) {
    f16x8u tmp;
    #pragma unroll
    for (int ii = 0; ii < 8; ++ii) {
      int bp = q_t * 8 + (((c_t + q_t) & 7) ^ ii);
      tmp.s[ii] = *(const unsigned short*)(smem + w * 4096 + ii * 512 + bp * 16 + a_t * 2);
    }
    vreg[w] = tmp.v;
  }

  #pragma unroll 1
  for (int rt = 0; rt < 3; ++rt) {
    if (rt > 0) {
      if (tid < 32) {                 // softmax over c per (w, ii)
        int wv = tid >> 3, ii = tid & 7;
        float l[8];
        #pragma unroll
        for (int c = 0; c < 8; ++c) l[c] = logitL[(wv * 8 + ii) * 8 + c];
        float mx = fmaxf(fmaxf(fmaxf(l[0], l[1]), fmaxf(l[2], l[3])),
                         fmaxf(fmaxf(l[4], l[5]), fmaxf(l[6], l[7])));
        float den = 0.f;
        #pragma unroll
        for (int c = 0; c < 8; ++c) den += __expf(l[c] - mx);
        float inv = 1.f / den;
        #pragma unroll
        for (int c = 0; c < 8; ++c)
          ((unsigned short*)(smem + 19456))[(wv * 8 + c) * 8 + ii] =
              f2h(__expf(l[c] - mx) * inv);
      }
      __syncthreads();
    }
    // weighted sum + squash; thread owns ch = tid
    #pragma unroll
    for (int w = 0; w < 4; ++w) {
      f16x8u rp, vv;
      rp.v = *(const f16x8*)(smem + 19456 + ((w * 8 + c_t) * 8) * 2);
      vv.v = vreg[w];
      float pre = bv;
      #pragma unroll
      for (int d = 0; d < 4; ++d)
        pre = __builtin_amdgcn_fdot2(vv.d[d], rp.d[d], pre, false);
      float nsq = pre * pre;
      #pragma unroll
      for (int m = 16; m >= 1; m >>= 1) nsq += __shfl_xor(nsq, m, 64);
      float av = pre * (sqrtf(nsq) / (1.f + nsq));
      if (rt == 2)
        out[((size_t)((bb * 32 + h) * 32 + wq * 4 + w)) * 256 + tid] = av;
      else
        *(unsigned short*)(smem + 16384 + w * 512 + q_t * 128 + c_t * 16 + a_t * 2) = f2h(av);
    }
    if (rt < 2) {
      __syncthreads();
      // agreement: thread (w,ii,c) -> logit via 16 fdot2, no shuffles
      float dot = 0.f;
      #pragma unroll
      for (int q = 0; q < 4; ++q) {
        f16x8u vv, aa;
        vv.v = *(const f16x8*)(smem + aw * 4096 + aii * 512 +
                               (q * 8 + (((ac + q) & 7) ^ aii)) * 16);
        aa.v = *(const f16x8*)(smem + 16384 + aw * 512 + q * 128 + ac * 16);
        #pragma unroll
        for (int d = 0; d < 4; ++d)
          dot = __builtin_amdgcn_fdot2(vv.d[d], aa.d[d], dot, false);
      }
      int idx = (aw * 8 + aii) * 8 + ac;
      if (rt == 0) logitL[idx] = dot;
      else         logitL[idx] += dot;
      __syncthreads();
    }
  }
}

extern "C" void kernel_launch(void* const* d_in, const int* in_sizes, int n_in,
                              void* d_out, int out_size, void* d_ws, size_t ws_size,
                              hipStream_t stream) {
  (void)in_sizes; (void)n_in; (void)ws_size; (void)out_size;
  const float* inp  = (const float*)d_in[0];
  const float* W    = (const float*)d_in[1];
  const float* bv   = (const float*)d_in[2];
  float* out        = (float*)d_out;
  unsigned short* wsh = (unsigned short*)d_ws;   // 204800 B used

  hipLaunchKernelGGL(wprep_kernel, dim3(400), dim3(256), 0, stream, W, wsh);
  hipLaunchKernelGGL(capsconv_mfma_kernel, dim3(4096), dim3(256), 0, stream,
                     inp, wsh, bv, out);
}

// Round 10
// 64.225 us; speedup vs baseline: 1.2968x; 1.0177x over previous
//
#include <hip/hip_runtime.h>

// ConvCapsuleLayer r10: r9 + ILP-restructured conv (per-kh batched loads, big VGPR budget).
// Block = 256 thr (4 waves), M=32 rows (4 w-pos x 8 ii), N=256 ch.
// Conv: per kh, issue 5 afrag + 10 bfrag loads, then 10 MFMA -> L2 latency hidden.
// Routing on v_dot2_f32_f16 (shuffle-free agreement), unchanged from r9.

typedef __attribute__((ext_vector_type(2))) _Float16 f16x2;
typedef __attribute__((ext_vector_type(8))) _Float16 f16x8;
typedef __attribute__((ext_vector_type(16))) float f32x16;

union f16x8u { f16x8 v; f16x2 d[4]; unsigned short s[8]; unsigned long long u[2]; };

__device__ __forceinline__ unsigned short f2h(float x) {
  union { _Float16 h; unsigned short u; } v;
  v.h = (_Float16)x;
  return v.u;
}

// W[5][5][16][256] f32 -> wsh fp16 [khkw 25][ch 256][ia 16]
__global__ __launch_bounds__(256) void wprep_kernel(
    const float* __restrict__ W, unsigned short* __restrict__ wsh) {
  int t = blockIdx.x * 256 + threadIdx.x;      // 102400 total
  int khkw = t >> 12;
  int rem  = t & 4095;
  int ch = rem >> 4, ia = rem & 15;
  wsh[t] = f2h(W[khkw * 4096 + ia * 256 + ch]);
}

// LDS map (19968 B):
//   conv phase:  X fp16 [kh 5][ii 8, stride 272B][wl 8][ia 16] = 10880 B @0
//   routing:     votesT fp16 [w 4][ii 8][chunk 32][a 8] = 16384 @0 (aliases X)
//                  chunk(q,c,ii) = q*8 + (((c+q)&7) ^ ii)   (bank spread, bijective)
//                actT  fp16 [w 4][q 4][c 8][a 8] = 2048 @16384
//                logitL f32 [w 4][ii 8][c 8]     = 1024 @18432
//                routeH fp16 [w 4][c 8][ii 8]    =  512 @19456
__global__ __launch_bounds__(256, 2) void capsconv_mfma_kernel(
    const float* __restrict__ inp,            // [16][32][32][8][16] f32
    const unsigned short* __restrict__ wsh,   // [25][256][16] fp16
    const float* __restrict__ bias,           // [256] f32
    float* __restrict__ out)                  // [16][32][32][256] f32
{
  __shared__ char smem[19968];
  const _Float16* wshh = (const _Float16*)wsh;
  float* logitL = (float*)(smem + 18432);

  const int tid  = threadIdx.x;
  const int wid  = tid >> 6;          // wave 0..3 -> ch quarter
  const int lane = tid & 63;
  const int sub  = lane >> 5;
  const int ln31 = lane & 31;

  const int bid = blockIdx.x;         // 4096 = ((bb*32 + h)*8 + wq)
  const int wq = bid & 7;
  const int h  = (bid >> 3) & 31;
  const int bb = bid >> 8;
  const int i_src  = bb >> 1;         // TF reshape scramble (verified r1/r4)
  const int b_base = (bb & 1) * 8;

  // ---------------- stage 5 X rows, PO2 decode (1280 quads) ----------------
  #pragma unroll
  for (int s = 0; s < 5; ++s) {
    int e = tid + s * 256;
    int kh  = e >> 8;
    int ii  = (e >> 5) & 7;
    int wl  = (e >> 2) & 7;
    int iaq = e & 3;
    int hh = h + kh - 2;
    int wsrc = wq * 4 + wl - 2;
    float4 v = make_float4(0.f, 0.f, 0.f, 0.f);
    if ((unsigned)hh < 32u && (unsigned)wsrc < 32u)
      v = *(const float4*)(inp +
          ((((size_t)(b_base + ii) * 32 + hh) * 32 + wsrc) * 8 + i_src) * 16 + iaq * 4);
    union { _Float16 hx[4]; unsigned long long u; } pk;
    pk.hx[0] = (_Float16)v.x; pk.hx[1] = (_Float16)v.y;
    pk.hx[2] = (_Float16)v.z; pk.hx[3] = (_Float16)v.w;
    *(unsigned long long*)(smem + kh * 2176 + ii * 272 + wl * 32 + iaq * 8) = pk.u;
  }
  __syncthreads();

  // ---------------- conv: 25 taps, per-kh batched loads (ILP) ----------------
  f32x16 acc[2];
  #pragma unroll
  for (int nt = 0; nt < 2; ++nt)
    #pragma unroll
    for (int e = 0; e < 16; ++e) acc[nt][e] = 0.f;

  const char* aBase = smem + (ln31 & 7) * 272 + (ln31 >> 3) * 32 + sub * 16;
  const _Float16* bBase = wshh + (wid * 64 + ln31) * 16 + sub * 8;

  #pragma unroll
  for (int kh = 0; kh < 5; ++kh) {
    f16x8 af[5], bf0[5], bf1[5];
    #pragma unroll
    for (int kw = 0; kw < 5; ++kw) {
      af[kw]  = *(const f16x8*)(aBase + kh * 2176 + kw * 32);
      bf0[kw] = *(const f16x8*)(bBase + (size_t)(kh * 5 + kw) * 4096);
      bf1[kw] = *(const f16x8*)(bBase + (size_t)(kh * 5 + kw) * 4096 + 512);
    }
    #pragma unroll
    for (int kw = 0; kw < 5; ++kw) {
      acc[0] = __builtin_amdgcn_mfma_f32_32x32x16_f16(af[kw], bf0[kw], acc[0], 0, 0, 0);
      acc[1] = __builtin_amdgcn_mfma_f32_32x32x16_f16(af[kw], bf1[kw], acc[1], 0, 0, 0);
    }
  }

  // ---------------- votes -> votesT [w][ii][chunk][a] ----------------
  __syncthreads();   // X region dead; votesT aliases it
  ((unsigned short*)(smem + 19456))[tid] = 0x3000;   // routeH = 0.125 (exact fp16)
  #pragma unroll
  for (int nt = 0; nt < 2; ++nt) {
    int ch = wid * 64 + nt * 32 + ln31;
    int c = (ch >> 5) & 7, q = (ch >> 3) & 3, a = ch & 7;
    #pragma unroll
    for (int w = 0; w < 4; ++w)
      #pragma unroll
      for (int t = 0; t < 4; ++t) {
        int ii = t + 4 * sub;          // C/D row = t + 8w + 4sub (verified r4-r7)
        int bp = q * 8 + (((c + q) & 7) ^ ii);
        *(unsigned short*)(smem + w * 4096 + ii * 512 + bp * 16 + a * 2) =
            f2h(acc[nt][w * 4 + t]);
      }
  }
  __syncthreads();

  // ---------------- routing ----------------
  const int c_t = (tid >> 5) & 7;     // owned channel decode (ch = tid)
  const int q_t = (tid >> 3) & 3;
  const int a_t = tid & 7;
  const float bv = bias[tid];
  const int aw  = tid >> 6;           // agreement task (w, ii, c)
  const int aii = (tid >> 3) & 7;
  const int ac  = tid & 7;

  // vreg[w][ii] = votes for owned ch (one-time gather from votesT)
  f16x8 vreg[4];
  #pragma unroll
  for (int w = 0; w < 4; ++w) {
    f16x8u tmp;
    #pragma unroll
    for (int ii = 0; ii < 8; ++ii) {
      int bp = q_t * 8 + (((c_t + q_t) & 7) ^ ii);
      tmp.s[ii] = *(const unsigned short*)(smem + w * 4096 + ii * 512 + bp * 16 + a_t * 2);
    }
    vreg[w] = tmp.v;
  }

  #pragma unroll 1
  for (int rt = 0; rt < 3; ++rt) {
    if (rt > 0) {
      if (tid < 32) {                 // softmax over c per (w, ii)
        int wv = tid >> 3, ii = tid & 7;
        float l[8];
        #pragma unroll
        for (int c = 0; c < 8; ++c) l[c] = logitL[(wv * 8 + ii) * 8 + c];
        float mx = fmaxf(fmaxf(fmaxf(l[0], l[1]), fmaxf(l[2], l[3])),
                         fmaxf(fmaxf(l[4], l[5]), fmaxf(l[6], l[7])));
        float den = 0.f;
        #pragma unroll
        for (int c = 0; c < 8; ++c) den += __expf(l[c] - mx);
        float inv = 1.f / den;
        #pragma unroll
        for (int c = 0; c < 8; ++c)
          ((unsigned short*)(smem + 19456))[(wv * 8 + c) * 8 + ii] =
              f2h(__expf(l[c] - mx) * inv);
      }
      __syncthreads();
    }
    // weighted sum + squash; thread owns ch = tid
    #pragma unroll
    for (int w = 0; w < 4; ++w) {
      f16x8u rp, vv;
      rp.v = *(const f16x8*)(smem + 19456 + ((w * 8 + c_t) * 8) * 2);
      vv.v = vreg[w];
      float pre = bv;
      #pragma unroll
      for (int d = 0; d < 4; ++d)
        pre = __builtin_amdgcn_fdot2(vv.d[d], rp.d[d], pre, false);
      float nsq = pre * pre;
      #pragma unroll
      for (int m = 16; m >= 1; m >>= 1) nsq += __shfl_xor(nsq, m, 64);
      float av = pre * (sqrtf(nsq) / (1.f + nsq));
      if (rt == 2)
        out[((size_t)((bb * 32 + h) * 32 + wq * 4 + w)) * 256 + tid] = av;
      else
        *(unsigned short*)(smem + 16384 + w * 512 + q_t * 128 + c_t * 16 + a_t * 2) = f2h(av);
    }
    if (rt < 2) {
      __syncthreads();
      // agreement: thread (w,ii,c) -> logit via 16 fdot2, no shuffles
      float dot = 0.f;
      #pragma unroll
      for (int q = 0; q < 4; ++q) {
        f16x8u vv, aa;
        vv.v = *(const f16x8*)(smem + aw * 4096 + aii * 512 +
                               (q * 8 + (((ac + q) & 7) ^ aii)) * 16);
        aa.v = *(const f16x8*)(smem + 16384 + aw * 512 + q * 128 + ac * 16);
        #pragma unroll
        for (int d = 0; d < 4; ++d)
          dot = __builtin_amdgcn_fdot2(vv.d[d], aa.d[d], dot, false);
      }
      int idx = (aw * 8 + aii) * 8 + ac;
      if (rt == 0) logitL[idx] = dot;
      else         logitL[idx] += dot;
      __syncthreads();
    }
  }
}

extern "C" void kernel_launch(void* const* d_in, const int* in_sizes, int n_in,
                              void* d_out, int out_size, void* d_ws, size_t ws_size,
                              hipStream_t stream) {
  (void)in_sizes; (void)n_in; (void)ws_size; (void)out_size;
  const float* inp  = (const float*)d_in[0];
  const float* W    = (const float*)d_in[1];
  const float* bv   = (const float*)d_in[2];
  float* out        = (float*)d_out;
  unsigned short* wsh = (unsigned short*)d_ws;   // 204800 B used

  hipLaunchKernelGGL(wprep_kernel, dim3(400), dim3(256), 0, stream, W, wsh);
  hipLaunchKernelGGL(capsconv_mfma_kernel, dim3(4096), dim3(256), 0, stream,
                     inp, wsh, bv, out);
}

// Round 11
// 54.895 us; speedup vs baseline: 1.5172x; 1.1700x over previous
//
#include <hip/hip_runtime.h>

// ConvCapsuleLayer r11: routing serial chains excised.
// - scale-factored squash: dot(votes,act) = scale(w,c)*dot(votes,pre); no shfl squash.
// - vreg assembled via lane^32 shfl of packed fp16 (lanes L/L+32 hold same ch).
// - votesT ii-stride 544B -> agreement reads <=2-way banked (free).
// Conv unchanged from r10 (fp16 MFMA 32x32x16, M=32 x N=256 per 256-thr block).

typedef __attribute__((ext_vector_type(2))) _Float16 f16x2;
typedef __attribute__((ext_vector_type(8))) _Float16 f16x8;
typedef __attribute__((ext_vector_type(16))) float f32x16;

union f16x8u { f16x8 v; f16x2 d[4]; unsigned short s[8]; unsigned int u32[4]; unsigned long long u[2]; };
union f16x2u { f16x2 v; unsigned int u; unsigned short s[2]; };

__device__ __forceinline__ unsigned short f2h(float x) {
  union { _Float16 h; unsigned short u; } v;
  v.h = (_Float16)x;
  return v.u;
}

// W[5][5][16][256] f32 -> wsh fp16 [khkw 25][ch 256][ia 16]
__global__ __launch_bounds__(256) void wprep_kernel(
    const float* __restrict__ W, unsigned short* __restrict__ wsh) {
  int t = blockIdx.x * 256 + threadIdx.x;      // 102400 total
  int khkw = t >> 12;
  int rem  = t & 4095;
  int ch = rem >> 4, ia = rem & 15;
  wsh[t] = f2h(W[khkw * 4096 + ia * 256 + ch]);
}

// LDS map (21120 B):
//   conv phase:  X fp16 [kh 5][ii 8, stride 272B][wl 8][ia 16] = 10880 B @0
//   routing:     votesT fp16 [w 4, stride 4352][ii 8, stride 544][chunk 32][a 8] @0
//                  chunk(q,c,ii) = q*8 + (((c+q)&7) ^ ii); stride 544 => banked <=2-way
//                preT  fp16 [w 4][q 4][c 8][a 8] = 2048 @17408
//                logitL f32 [w 4][ii 8][c 8]     = 1024 @19456
//                routeH fp16 [w 4][c 8][ii 8]    =  512 @20480
//                scaleL f32 [w 4][c 8]           =  128 @20992
__global__ __launch_bounds__(256, 2) void capsconv_mfma_kernel(
    const float* __restrict__ inp,            // [16][32][32][8][16] f32
    const unsigned short* __restrict__ wsh,   // [25][256][16] fp16
    const float* __restrict__ bias,           // [256] f32
    float* __restrict__ out)                  // [16][32][32][256] f32
{
  __shared__ char smem[21120];
  const _Float16* wshh = (const _Float16*)wsh;
  float* logitL = (float*)(smem + 19456);
  float* scaleL = (float*)(smem + 20992);

  const int tid  = threadIdx.x;
  const int wid  = tid >> 6;          // wave 0..3 -> ch quarter
  const int lane = tid & 63;
  const int sub  = lane >> 5;
  const int ln31 = lane & 31;

  const int bid = blockIdx.x;         // 4096 = ((bb*32 + h)*8 + wq)
  const int wq = bid & 7;
  const int h  = (bid >> 3) & 31;
  const int bb = bid >> 8;
  const int i_src  = bb >> 1;         // TF reshape scramble (verified r1/r4)
  const int b_base = (bb & 1) * 8;

  // ---------------- stage 5 X rows, PO2 decode (1280 quads) ----------------
  #pragma unroll
  for (int s = 0; s < 5; ++s) {
    int e = tid + s * 256;
    int kh  = e >> 8;
    int ii  = (e >> 5) & 7;
    int wl  = (e >> 2) & 7;
    int iaq = e & 3;
    int hh = h + kh - 2;
    int wsrc = wq * 4 + wl - 2;
    float4 v = make_float4(0.f, 0.f, 0.f, 0.f);
    if ((unsigned)hh < 32u && (unsigned)wsrc < 32u)
      v = *(const float4*)(inp +
          ((((size_t)(b_base + ii) * 32 + hh) * 32 + wsrc) * 8 + i_src) * 16 + iaq * 4);
    union { _Float16 hx[4]; unsigned long long u; } pkk;
    pkk.hx[0] = (_Float16)v.x; pkk.hx[1] = (_Float16)v.y;
    pkk.hx[2] = (_Float16)v.z; pkk.hx[3] = (_Float16)v.w;
    *(unsigned long long*)(smem + kh * 2176 + ii * 272 + wl * 32 + iaq * 8) = pkk.u;
  }
  __syncthreads();

  // ---------------- conv: 25 taps, per-kh batched loads ----------------
  f32x16 acc[2];
  #pragma unroll
  for (int nt = 0; nt < 2; ++nt)
    #pragma unroll
    for (int e = 0; e < 16; ++e) acc[nt][e] = 0.f;

  const char* aBase = smem + (ln31 & 7) * 272 + (ln31 >> 3) * 32 + sub * 16;
  const _Float16* bBase = wshh + (wid * 64 + ln31) * 16 + sub * 8;

  #pragma unroll
  for (int kh = 0; kh < 5; ++kh) {
    f16x8 af[5], bf0[5], bf1[5];
    #pragma unroll
    for (int kw = 0; kw < 5; ++kw) {
      af[kw]  = *(const f16x8*)(aBase + kh * 2176 + kw * 32);
      bf0[kw] = *(const f16x8*)(bBase + (size_t)(kh * 5 + kw) * 4096);
      bf1[kw] = *(const f16x8*)(bBase + (size_t)(kh * 5 + kw) * 4096 + 512);
    }
    #pragma unroll
    for (int kw = 0; kw < 5; ++kw) {
      acc[0] = __builtin_amdgcn_mfma_f32_32x32x16_f16(af[kw], bf0[kw], acc[0], 0, 0, 0);
      acc[1] = __builtin_amdgcn_mfma_f32_32x32x16_f16(af[kw], bf1[kw], acc[1], 0, 0, 0);
    }
  }

  // ---------------- pack acc -> fp16 pairs; assemble vreg via lane^32 shfl ----------------
  // acc[nt][w*4+t] = vote(w, ii = t + 4*sub, ch = wid*64 + nt*32 + ln31).
  // Lanes L and L^32 share ln31 -> same ch set, complementary ii halves.
  unsigned int pk[2][4][2];
  #pragma unroll
  for (int nt = 0; nt < 2; ++nt)
    #pragma unroll
    for (int w = 0; w < 4; ++w) {
      f16x2u lo, hi;
      lo.v = f16x2{(_Float16)acc[nt][w * 4 + 0], (_Float16)acc[nt][w * 4 + 1]};
      hi.v = f16x2{(_Float16)acc[nt][w * 4 + 2], (_Float16)acc[nt][w * 4 + 3]};
      pk[nt][w][0] = lo.u; pk[nt][w][1] = hi.u;
    }
  f16x8 vreg[4];   // vreg[w].s[ii] = vote(w, ii, ch = tid)
  #pragma unroll
  for (int w = 0; w < 4; ++w) {
    unsigned int own0 = sub ? pk[1][w][0] : pk[0][w][0];
    unsigned int own1 = sub ? pk[1][w][1] : pk[0][w][1];
    unsigned int snd0 = sub ? pk[0][w][0] : pk[1][w][0];
    unsigned int snd1 = sub ? pk[0][w][1] : pk[1][w][1];
    unsigned int rc0 = (unsigned int)__shfl_xor((int)snd0, 32, 64);
    unsigned int rc1 = (unsigned int)__shfl_xor((int)snd1, 32, 64);
    f16x8u vv;
    vv.u32[0] = sub ? rc0 : own0;   // ii 0,1
    vv.u32[1] = sub ? rc1 : own1;   // ii 2,3
    vv.u32[2] = sub ? own0 : rc0;   // ii 4,5
    vv.u32[3] = sub ? own1 : rc1;   // ii 6,7
    vreg[w] = vv.v;
  }

  // ---------------- votesT writes (transpose for agreement) ----------------
  __syncthreads();   // X region dead; votesT aliases it
  {
    const int cT = (tid >> 5) & 7, qT = (tid >> 3) & 3, aT = tid & 7;
    #pragma unroll
    for (int w = 0; w < 4; ++w) {
      f16x8u vv; vv.v = vreg[w];
      #pragma unroll
      for (int ii = 0; ii < 8; ++ii) {
        int bp = qT * 8 + (((cT + qT) & 7) ^ ii);
        *(unsigned short*)(smem + w * 4352 + ii * 544 + bp * 16 + aT * 2) = vv.s[ii];
      }
    }
  }
  ((unsigned short*)(smem + 20480))[tid] = 0x3000;   // routeH = 0.125 (exact fp16)
  __syncthreads();

  // ---------------- routing ----------------
  const int c_t = (tid >> 5) & 7;
  const int q_t = (tid >> 3) & 3;
  const int a_t = tid & 7;
  const float bv = bias[tid];
  const int aw  = tid >> 6;           // agreement task (w, ii, c)
  const int aii = (tid >> 3) & 7;
  const int ac  = tid & 7;

  float pre[4];
  #pragma unroll 1
  for (int rt = 0; rt < 3; ++rt) {
    if (rt > 0) {
      if (tid < 32) {                 // softmax over c per (w, ii)
        int wv = tid >> 3, ii = tid & 7;
        float l[8];
        #pragma unroll
        for (int c = 0; c < 8; ++c) l[c] = logitL[(wv * 8 + ii) * 8 + c];
        float mx = fmaxf(fmaxf(fmaxf(l[0], l[1]), fmaxf(l[2], l[3])),
                         fmaxf(fmaxf(l[4], l[5]), fmaxf(l[6], l[7])));
        float den = 0.f;
        #pragma unroll
        for (int c = 0; c < 8; ++c) den += __expf(l[c] - mx);
        float inv = 1.f / den;
        #pragma unroll
        for (int c = 0; c < 8; ++c)
          ((unsigned short*)(smem + 20480))[(wv * 8 + c) * 8 + ii] =
              f2h(__expf(l[c] - mx) * inv);
      }
      __syncthreads();
    }
    // weighted sum; write pre (NOT act) to preT
    #pragma unroll
    for (int w = 0; w < 4; ++w) {
      f16x8u rp, vv;
      rp.v = *(const f16x8*)(smem + 20480 + ((w * 8 + c_t) * 8) * 2);
      vv.v = vreg[w];
      float p = bv;
      #pragma unroll
      for (int d = 0; d < 4; ++d)
        p = __builtin_amdgcn_fdot2(vv.d[d], rp.d[d], p, false);
      pre[w] = p;
      *(unsigned short*)(smem + 17408 + w * 512 + q_t * 128 + c_t * 16 + a_t * 2) = f2h(p);
    }
    __syncthreads();
    // squash scale per (w,c): 32 threads, 16 independent fdot2
    if (tid < 32) {
      int wv = tid >> 3, cc = tid & 7;
      const char* pp = smem + 17408 + wv * 512 + cc * 16;
      f16x8u x0, x1, x2, x3;
      x0.v = *(const f16x8*)(pp);
      x1.v = *(const f16x8*)(pp + 128);
      x2.v = *(const f16x8*)(pp + 256);
      x3.v = *(const f16x8*)(pp + 384);
      float n0 = 0.f, n1 = 0.f, n2 = 0.f, n3 = 0.f;
      #pragma unroll
      for (int d = 0; d < 4; ++d) {
        n0 = __builtin_amdgcn_fdot2(x0.d[d], x0.d[d], n0, false);
        n1 = __builtin_amdgcn_fdot2(x1.d[d], x1.d[d], n1, false);
        n2 = __builtin_amdgcn_fdot2(x2.d[d], x2.d[d], n2, false);
        n3 = __builtin_amdgcn_fdot2(x3.d[d], x3.d[d], n3, false);
      }
      float nsq = (n0 + n1) + (n2 + n3);
      scaleL[tid] = sqrtf(nsq) / (1.f + nsq);
    }
    __syncthreads();
    if (rt < 2) {
      // agreement: thread (w,ii,c); dot(votes,pre) * scale -> logit
      float dot = 0.f;
      #pragma unroll
      for (int q = 0; q < 4; ++q) {
        f16x8u vv, aa;
        vv.v = *(const f16x8*)(smem + aw * 4352 + aii * 544 +
                               (q * 8 + (((ac + q) & 7) ^ aii)) * 16);
        aa.v = *(const f16x8*)(smem + 17408 + aw * 512 + q * 128 + ac * 16);
        #pragma unroll
        for (int d = 0; d < 4; ++d)
          dot = __builtin_amdgcn_fdot2(vv.d[d], aa.d[d], dot, false);
      }
      float ds = dot * scaleL[aw * 8 + ac];
      int idx = (aw * 8 + aii) * 8 + ac;
      if (rt == 0) logitL[idx] = ds;
      else         logitL[idx] += ds;
      __syncthreads();
    } else {
      #pragma unroll
      for (int w = 0; w < 4; ++w)
        out[((size_t)((bb * 32 + h) * 32 + wq * 4 + w)) * 256 + tid] =
            pre[w] * scaleL[w * 8 + c_t];
    }
  }
}

extern "C" void kernel_launch(void* const* d_in, const int* in_sizes, int n_in,
                              void* d_out, int out_size, void* d_ws, size_t ws_size,
                              hipStream_t stream) {
  (void)in_sizes; (void)n_in; (void)ws_size; (void)out_size;
  const float* inp  = (const float*)d_in[0];
  const float* W    = (const float*)d_in[1];
  const float* bv   = (const float*)d_in[2];
  float* out        = (float*)d_out;
  unsigned short* wsh = (unsigned short*)d_ws;   // 204800 B used

  hipLaunchKernelGGL(wprep_kernel, dim3(400), dim3(256), 0, stream, W, wsh);
  hipLaunchKernelGGL(capsconv_mfma_kernel, dim3(4096), dim3(256), 0, stream,
                     inp, wsh, bv, out);
}